// Round 4
// baseline (1229.183 us; speedup 1.0000x reference)
//
#include <hip/hip_runtime.h>

// Landmark (Nystrom) attention, MI355X/gfx950.
// B=2 T=8192 Dm=2048 H=16 Hkv=8 Dh=128 M=64 RANK=64 NIT=6
// Round 3 (resubmit after GPU acquisition timeout): GEMM k-loop ->
// read-one-phase-ahead + counted lgkm (no full drain); attn_mk -> 128-key
// chunks (2048 waves, 2x occupancy).

#define B_ 2
#define T_ 8192
#define DM 2048
#define H_ 16
#define DH 128
#define NIT 6

typedef unsigned short u16;
typedef __attribute__((ext_vector_type(8))) short bf16x8;
typedef __attribute__((ext_vector_type(4))) float f32x4;
typedef __attribute__((ext_vector_type(4))) unsigned short u16x4;

__device__ __forceinline__ u16 f2bf(float f) {
    unsigned u = __float_as_uint(f);
    u += 0x7FFFu + ((u >> 16) & 1u);
    return (u16)(u >> 16);
}

__device__ __forceinline__ void async16(const void* g, void* l) {
    __builtin_amdgcn_global_load_lds((const __attribute__((address_space(1))) void*)g,
                                     (__attribute__((address_space(3))) void*)l,
                                     16, 0, 0);
}

// ---------------- elementwise f32 -> bf16 ----------------
__global__ void cvt_x_kernel(const float* __restrict__ x, u16* __restrict__ xb, int n4) {
    int i = blockIdx.x * blockDim.x + threadIdx.x;
    int stride = gridDim.x * blockDim.x;
    for (; i < n4; i += stride) {
        float4 v = ((const float4*)x)[i];
        u16x4 o;
        o.x = f2bf(v.x); o.y = f2bf(v.y); o.z = f2bf(v.z); o.w = f2bf(v.w);
        ((u16x4*)xb)[i] = o;
    }
}

// ---------------- transpose + convert f32 (R x C) -> bf16 (C x R) ----------------
__global__ void tconv_kernel(const float* __restrict__ src, u16* __restrict__ dst, int R, int C) {
    __shared__ float tl[32][33];
    int c0 = blockIdx.x * 32, r0 = blockIdx.y * 32;
    int tx = threadIdx.x, ty = threadIdx.y;
    #pragma unroll
    for (int i = ty; i < 32; i += 8)
        tl[i][tx] = src[(size_t)(r0 + i) * C + c0 + tx];
    __syncthreads();
    #pragma unroll
    for (int i = ty; i < 32; i += 8)
        dst[(size_t)(c0 + i) * R + r0 + tx] = f2bf(tl[tx][i]);
}

// ---------------- transpose bf16 v (per b,g: [T][128] -> [128][T]) ----------------
__global__ void tv_kernel(const u16* __restrict__ v, u16* __restrict__ vT) {
    int bg = blockIdx.z;
    const u16* src = v + (size_t)(bg >> 3) * T_ * 1024 + (bg & 7) * DH;
    u16* dst = vT + (size_t)bg * DH * T_;
    __shared__ u16 tl[32][33];
    int t0 = blockIdx.x * 32, d0 = blockIdx.y * 32;
    int tx = threadIdx.x, ty = threadIdx.y;
    #pragma unroll
    for (int i = ty; i < 32; i += 8)
        tl[i][tx] = src[(size_t)(t0 + i) * 1024 + d0 + tx];
    __syncthreads();
    #pragma unroll
    for (int i = ty; i < 32; i += 8)
        dst[(size_t)(d0 + i) * T_ + t0 + tx] = tl[tx][i];
}

// ==================== 256x256 8-phase bf16 GEMM ====================
// Round-3 schedule: fragments for quadrant Q(p) are ds_read in phase p-1; the
// counted lgkmcnt(N) before the stage calls drains prior-phase reads so the
// stage DMA can't overwrite a region with a read in flight. No lgkmcnt(0)
// anywhere in the loop; compiler emits counted waits before MFMA (free).
// Phase map per tile t: ph1{RD A0,B0 | MFMA Q11(t-1)} ph2{RD B1 | Q00(t)}
//                       ph3{RD A1 | Q01(t)} ph4{RD none | VM6 | Q10(t)}
// Stages unchanged: ph1 A1(t+1), ph2 A0(t+2), ph3 B0(t+2), ph4 B1(t+2).

#define BAR()   __builtin_amdgcn_s_barrier()
#define SB0()   __builtin_amdgcn_sched_barrier(0)
#define LGKM(n) asm volatile("s_waitcnt lgkmcnt(" #n ")" ::: "memory")
#define VM6()   asm volatile("s_waitcnt vmcnt(6)" ::: "memory")

#define RD_A(S, BUF, H) do {                                                  \
    const char* _p = lA_rd + (BUF) * 32768 + (H) * 16384;                     \
    _Pragma("unroll") for (int _m = 0; _m < 4; ++_m) {                        \
        Af[S][_m][0] = *(const bf16x8*)(_p + _m * 2048 + kswz0);              \
        Af[S][_m][1] = *(const bf16x8*)(_p + _m * 2048 + kswz1);              \
    }                                                                         \
} while (0)

#define RD_B(S, BUF, H) do {                                                  \
    const char* _p = lB_rd + (BUF) * 32768 + (H) * 16384;                     \
    _Pragma("unroll") for (int _n = 0; _n < 2; ++_n) {                        \
        Bf[S][_n][0] = *(const bf16x8*)(_p + _n * 2048 + kswz0);              \
        Bf[S][_n][1] = *(const bf16x8*)(_p + _n * 2048 + kswz1);              \
    }                                                                         \
} while (0)

#define ST_A(BUF, H, T) do {                                                  \
    const u16* _g = gA + (size_t)(H) * 64 * K + (size_t)(T) * 64;             \
    char* _l = lsAst + (BUF) * 32768 + (H) * 16384;                           \
    async16(_g, _l);                                                          \
    async16(_g + (size_t)128 * K, _l + 8192);                                 \
} while (0)

#define ST_B(BUF, H, T) do {                                                  \
    const u16* _g = gB + (size_t)(H) * 32 * K + (size_t)(T) * 64;             \
    char* _l = lsBst + (BUF) * 32768 + (H) * 16384;                           \
    async16(_g, _l);                                                          \
    async16(_g + (size_t)128 * K, _l + 8192);                                 \
} while (0)

#define MFMA_Q(AM, BN)                                                        \
    _Pragma("unroll") for (int _m = 0; _m < 4; ++_m)                          \
    _Pragma("unroll") for (int _n = 0; _n < 2; ++_n)                          \
    _Pragma("unroll") for (int _k = 0; _k < 2; ++_k)                          \
        acc[(AM) * 4 + _m][(BN) * 2 + _n] =                                   \
            __builtin_amdgcn_mfma_f32_16x16x32_bf16(                          \
                Af[AM][_m][_k], Bf[BN][_n][_k],                               \
                acc[(AM) * 4 + _m][(BN) * 2 + _n], 0, 0, 0);

template<int MODE>
__global__ __launch_bounds__(512) void gemm256_kernel(
    const u16* __restrict__ A, const u16* __restrict__ Bt,
    u16* __restrict__ oq, u16* __restrict__ ok, u16* __restrict__ ov,
    float* __restrict__ of, int K, int nxt)
{
    __shared__ u16 lsA[2][2][128][64];   // [buf][half][row][k]
    __shared__ u16 lsB[2][2][128][64];

    const int tid  = threadIdx.x;
    const int lane = tid & 63;
    const int w    = tid >> 6;
    const int wr   = w >> 2, wc = w & 3;
    const int fr   = lane & 15, fg = lane >> 4;

    // T1: bijective XCD swizzle (gridDim.x % 8 == 0)
    const int cpx = (int)gridDim.x >> 3;
    const int bid = ((int)blockIdx.x & 7) * cpx + ((int)blockIdx.x >> 3);
    const int bx = bid % nxt, by = bid / nxt;
    const long R0 = (long)by * 256, C0 = (long)bx * 256;

    // staging addressing: thread tid covers LDS bytes [i*8192 + tid*16, +16)
    const int sr = tid >> 3;
    const int sc = tid & 7;
    const int koff = ((sc ^ (sr & 7)) * 8);   // pre-swizzled global k offset
    const u16* gA = A  + (R0 + sr) * (size_t)K + koff;
    const u16* gB = Bt + (C0 + (sr >> 5) * 64 + (sr & 31)) * (size_t)K + koff;
    char* lsAst = (char*)lsA + w * 1024;
    char* lsBst = (char*)lsB + w * 1024;

    // ds_read addressing (swizzled)
    const int kswz0 = (0 * 64 + fg * 16) ^ ((fr & 7) << 4);
    const int kswz1 = (1 * 64 + fg * 16) ^ ((fr & 7) << 4);
    const char* lA_rd = (const char*)lsA + (wr * 64 + fr) * 128;
    const char* lB_rd = (const char*)lsB + (wc * 32 + fr) * 128;

    f32x4 acc[8][4] = {};
    bf16x8 Af[2][4][2], Bf[2][2][2];

    const int NT = K >> 6;

    // prologue: tile0 (A0,B0,B1,A1) + tile1 (A0,B0,B1); vmcnt(6) -> tile0 landed
    ST_A(0, 0, 0); ST_B(0, 0, 0); ST_B(0, 1, 0); ST_A(0, 1, 0);
    ST_A(1, 0, 1); ST_B(1, 0, 1); ST_B(1, 1, 1);
    VM6();
    BAR(); SB0();

    for (int t = 0; t < NT; ++t) {
        const int buf = t & 1;
        // -- phase 1: RD A0(t)+B0(t) [for Q00@ph2]; drain prior reads; stage A1(t+1); MFMA Q11(t-1)
        RD_A(0, buf, 0);
        RD_B(0, buf, 0);
        LGKM(12);
        if (t + 1 < NT) ST_A(buf ^ 1, 1, t + 1);
        BAR(); SB0();
        __builtin_amdgcn_s_setprio(1);
        if (t > 0) { MFMA_Q(1, 1); }
        __builtin_amdgcn_s_setprio(0);
        BAR(); SB0();
        // -- phase 2: RD B1(t) [for Q01@ph3]; stage A0(t+2); MFMA Q00(t)
        RD_B(1, buf, 1);
        LGKM(4);
        if (t + 2 < NT) ST_A(buf, 0, t + 2);
        BAR(); SB0();
        __builtin_amdgcn_s_setprio(1);
        MFMA_Q(0, 0);
        __builtin_amdgcn_s_setprio(0);
        BAR(); SB0();
        // -- phase 3: RD A1(t) [for Q10@ph4]; stage B0(t+2); MFMA Q01(t)
        RD_A(1, buf, 1);
        LGKM(8);
        if (t + 2 < NT) ST_B(buf, 0, t + 2);
        BAR(); SB0();
        __builtin_amdgcn_s_setprio(1);
        MFMA_Q(0, 1);
        __builtin_amdgcn_s_setprio(0);
        BAR(); SB0();
        // -- phase 4: no reads; stage B1(t+2); vmcnt(6); MFMA Q10(t)
        if (t + 2 < NT) ST_B(buf, 1, t + 2);
        VM6();
        BAR(); SB0();
        __builtin_amdgcn_s_setprio(1);
        MFMA_Q(1, 0);
        __builtin_amdgcn_s_setprio(0);
        BAR(); SB0();
    }
    // final quadrant of last tile
    MFMA_Q(1, 1);

    // epilogue
    const long rb0 = R0 + wr * 128 + fg * 4;
    const int  cb0 = (int)C0 + wc * 64 + fr;
    #pragma unroll
    for (int mi = 0; mi < 8; ++mi)
        #pragma unroll
        for (int ni = 0; ni < 4; ++ni)
            #pragma unroll
            for (int rr = 0; rr < 4; ++rr) {
                long rg = rb0 + mi * 16 + rr;
                int  nn = cb0 + ni * 16;
                float val = acc[mi][ni][rr];
                if (MODE == 0) {
                    u16 o = f2bf(val);
                    if (nn < 2048)      oq[rg * 2048 + nn] = o;
                    else if (nn < 3072) ok[rg * 1024 + (nn - 2048)] = o;
                    else                ov[rg * 1024 + (nn - 3072)] = o;
                } else {
                    of[rg * 2048 + nn] = val;
                }
            }
}

// ---------------- exact f32 landmark GEMM: land_raw[128][3072] += x_land @ [Wq|Wk] ----------------
__global__ __launch_bounds__(256) void land_gemm_kernel(
    const float* __restrict__ x, const float* __restrict__ Wq,
    const float* __restrict__ Wk, float* __restrict__ land_raw)
{
    __shared__ float xs[128][36];
    __shared__ float ws[32][132];
    const int tid = threadIdx.x;
    const int n0 = blockIdx.x * 128;
    const int tm0 = (tid >> 4) * 8, tn0 = (tid & 15) * 8;
    float accr[8][8] = {};

    for (int it = 0; it < 8; ++it) {
        const int k0 = blockIdx.y * 256 + it * 32;
        __syncthreads();
        for (int idx = tid * 4; idx < 4096; idx += 1024) {
            int r = idx >> 5, c = idx & 31;
            *(float4*)&xs[r][c] =
                *(const float4*)&x[((size_t)(r >> 6) * T_ + (r & 63) * 128) * DM + k0 + c];
        }
        if (n0 < 2048) {
            for (int idx = tid * 4; idx < 4096; idx += 1024) {
                int k = idx >> 7, c = idx & 127;
                *(float4*)&ws[k][c] = *(const float4*)&Wq[(size_t)(k0 + k) * 2048 + n0 + c];
            }
        } else {
            for (int idx = tid * 4; idx < 4096; idx += 1024) {
                int k = idx >> 7, c = idx & 127;
                *(float4*)&ws[k][c] = *(const float4*)&Wk[(size_t)(k0 + k) * 1024 + (n0 - 2048) + c];
            }
        }
        __syncthreads();
        for (int k = 0; k < 32; ++k) {
            float a[8];
            #pragma unroll
            for (int i = 0; i < 8; ++i) a[i] = xs[tm0 + i][k];
            f32x4 b0 = *(const f32x4*)&ws[k][tn0];
            f32x4 b1 = *(const f32x4*)&ws[k][tn0 + 4];
            #pragma unroll
            for (int i = 0; i < 8; ++i) {
                accr[i][0] += a[i] * b0[0]; accr[i][1] += a[i] * b0[1];
                accr[i][2] += a[i] * b0[2]; accr[i][3] += a[i] * b0[3];
                accr[i][4] += a[i] * b1[0]; accr[i][5] += a[i] * b1[1];
                accr[i][6] += a[i] * b1[2]; accr[i][7] += a[i] * b1[3];
            }
        }
    }
    for (int i = 0; i < 8; ++i)
        for (int j = 0; j < 8; ++j)
            atomicAdd(&land_raw[(size_t)(tm0 + i) * 3072 + n0 + tn0 + j], accr[i][j]);
}

// ---------------- kernel_proj on landmarks (f32 exact) ----------------
__global__ void proj_kernel(const float* __restrict__ land_raw,
    const float* __restrict__ Wkp1, const float* __restrict__ Wkp2,
    float* __restrict__ qlf, float* __restrict__ klf,
    u16* __restrict__ qlb, u16* __restrict__ klb)
{
    const int bid = blockIdx.x;
    const int type = bid & 1;
    const int m = (bid >> 1) & 63;
    const int bh = bid >> 7;
    const int b = bh >> 4, h = bh & 15;
    const int lane = threadIdx.x;
    const int lm = b * 64 + m;
    const float* src = (type == 0)
        ? land_raw + (size_t)lm * 3072 + h * 128
        : land_raw + (size_t)lm * 3072 + 2048 + (h >> 1) * 128;
    __shared__ float zb[128];
    __shared__ float sb[64];
    float z0 = src[lane], z1 = src[lane + 64];
    zb[lane] = z0; zb[lane + 64] = z1;
    __syncthreads();
    float hsum = 0.f;
    #pragma unroll 4
    for (int d = 0; d < 128; ++d) hsum += zb[d] * Wkp1[d * 64 + lane];
    sb[lane] = hsum / (1.f + __expf(-hsum));
    __syncthreads();
    float o0 = z0, o1 = z1;
    #pragma unroll 4
    for (int j = 0; j < 64; ++j) {
        float sj = sb[j];
        o0 += sj * Wkp2[j * 128 + lane];
        o1 += sj * Wkp2[j * 128 + lane + 64];
    }
    size_t oidx = ((size_t)bh * 64 + m) * 128 + lane;
    float* fo = (type == 0) ? qlf : klf;
    u16*   bo = (type == 0) ? qlb : klb;
    fo[oidx] = o0; fo[oidx + 64] = o1;
    bo[oidx] = f2bf(o0); bo[oidx + 64] = f2bf(o1);
}

// ---------------- K_mm softmax + Newton pinv (f32, one block per bh) ----------------
__global__ __launch_bounds__(256) void pinv_kernel(
    const float* __restrict__ qlf, const float* __restrict__ klf, float* __restrict__ inv)
{
    const int bh = blockIdx.x;
    const int tid = threadIdx.x;
    const int m = tid >> 2, nq = tid & 3, n0b = nq * 16;
    __shared__ float Am[64][68];
    __shared__ float Z[64][68];
    __shared__ float Wm[64][68];
    __shared__ float cs[64], rsn[64];
    __shared__ float vsc;
    const float scale = 0.08838834764831845f;

    float accr[16] = {};
    const float* qrow = qlf + ((size_t)bh * 64 + m) * 128;
    for (int dc = 0; dc < 4; ++dc) {
        f32x4 qv[8];
        #pragma unroll
        for (int u = 0; u < 8; ++u) qv[u] = *(const f32x4*)&qrow[dc * 32 + u * 4];
        for (int nn = 0; nn < 16; ++nn) {
            const float* kp = klf + ((size_t)bh * 64 + n0b + nn) * 128 + dc * 32;
            float s = 0.f;
            #pragma unroll
            for (int u = 0; u < 8; ++u) {
                f32x4 kv = *(const f32x4*)&kp[u * 4];
                s += qv[u][0]*kv[0] + qv[u][1]*kv[1] + qv[u][2]*kv[2] + qv[u][3]*kv[3];
            }
            accr[nn] += s;
        }
    }
    float rsum = 0.f;
    #pragma unroll
    for (int nn = 0; nn < 16; ++nn) { accr[nn] = __expf(accr[nn] * scale); rsum += accr[nn]; }
    rsum += __shfl_xor(rsum, 1);
    rsum += __shfl_xor(rsum, 2);
    float rinv = 1.f / rsum;
    #pragma unroll
    for (int nn = 0; nn < 16; ++nn) Am[m][n0b + nn] = accr[nn] * rinv;
    __syncthreads();
    if (tid < 64) {
        float s = 0.f;
        for (int i = 0; i < 64; ++i) s += Am[i][tid];
        cs[tid] = s;
    } else if (tid < 128) {
        int r = tid - 64; float s = 0.f;
        for (int j = 0; j < 64; ++j) s += Am[r][j];
        rsn[r] = s;
    }
    __syncthreads();
    if (tid == 0) {
        float n1 = 0.f, ni = 0.f;
        for (int i = 0; i < 64; ++i) { n1 = fmaxf(n1, cs[i]); ni = fmaxf(ni, rsn[i]); }
        float pr = n1 * ni; if (pr < 1e-7f) pr = 1e-7f;
        vsc = 1.f / pr;
    }
    __syncthreads();
    {
        float v = vsc;
        for (int u = 0; u < 16; ++u) {
            int idx = tid * 16 + u;
            Z[idx >> 6][idx & 63] = Am[idx & 63][idx >> 6] * v;
        }
    }
    for (int it = 0; it < NIT; ++it) {
        __syncthreads();
        float wacc[16] = {};
        for (int k = 0; k < 64; ++k) {
            float a = Am[m][k];
            f32x4 z0 = *(const f32x4*)&Z[k][n0b];
            f32x4 z1 = *(const f32x4*)&Z[k][n0b + 4];
            f32x4 z2 = *(const f32x4*)&Z[k][n0b + 8];
            f32x4 z3 = *(const f32x4*)&Z[k][n0b + 12];
            #pragma unroll
            for (int u = 0; u < 4; ++u) {
                wacc[u]      += a * z0[u];
                wacc[u + 4]  += a * z1[u];
                wacc[u + 8]  += a * z2[u];
                wacc[u + 12] += a * z3[u];
            }
        }
        #pragma unroll
        for (int nn = 0; nn < 16; ++nn) Wm[m][n0b + nn] = wacc[nn];
        __syncthreads();
        float zacc[16] = {};
        for (int k = 0; k < 64; ++k) {
            float zk = Z[m][k];
            f32x4 w0 = *(const f32x4*)&Wm[k][n0b];
            f32x4 w1 = *(const f32x4*)&Wm[k][n0b + 4];
            f32x4 w2 = *(const f32x4*)&Wm[k][n0b + 8];
            f32x4 w3 = *(const f32x4*)&Wm[k][n0b + 12];
            #pragma unroll
            for (int u = 0; u < 4; ++u) {
                zacc[u]      += zk * w0[u];
                zacc[u + 4]  += zk * w1[u];
                zacc[u + 8]  += zk * w2[u];
                zacc[u + 12] += zk * w3[u];
            }
        }
        #pragma unroll
        for (int nn = 0; nn < 16; ++nn) zacc[nn] = 2.f * Z[m][n0b + nn] - zacc[nn];
        __syncthreads();
        #pragma unroll
        for (int nn = 0; nn < 16; ++nn) Z[m][n0b + nn] = zacc[nn];
    }
    __syncthreads();
    for (int u = 0; u < 16; ++u) {
        int idx = tid * 16 + u;
        inv[(size_t)bh * 4096 + idx] = Z[idx >> 6][idx & 63];
    }
}

// ---------------- K_mk @ v flash chunks (1 wave / block, 128 keys/chunk) ----------------
__global__ __launch_bounds__(64) void attn_mk_kernel(
    const u16* __restrict__ qlb, const u16* __restrict__ kb,
    const u16* __restrict__ vT, float* __restrict__ agg_acc, float* __restrict__ agg_sum)
{
    const int bid = blockIdx.x;
    const int chunk = bid & 63;          // 64 chunks x 128 keys
    const int bh = bid >> 6;
    const int b = bh >> 4, h = bh & 15, g = h >> 1;
    const int t0 = chunk * 128;
    const int lane = threadIdx.x;
    const int fr = lane & 15, fg = lane >> 4;
    const float scale = 0.08838834764831845f;
    __shared__ u16 P[64][136];

    float rst[4][4] = {};
    const u16* qbase = qlb + ((size_t)bh * 64 + fr) * 128 + fg * 8;

    for (int sc = 0; sc < 2; ++sc) {
        f32x4 S[4][4] = {};
        const u16* kbase = kb + ((size_t)(b * T_ + t0 + sc * 64 + fr)) * 1024 + g * 128 + fg * 8;
        #pragma unroll
        for (int ks = 0; ks < 4; ++ks) {
            bf16x8 a[4], bv[4];
            #pragma unroll
            for (int i = 0; i < 4; ++i) a[i] = *(const bf16x8*)(qbase + (size_t)i * 16 * 128 + ks * 32);
            #pragma unroll
            for (int j = 0; j < 4; ++j) bv[j] = *(const bf16x8*)(kbase + (size_t)j * 16 * 1024 + ks * 32);
            #pragma unroll
            for (int i = 0; i < 4; ++i)
                #pragma unroll
                for (int j = 0; j < 4; ++j)
                    S[i][j] = __builtin_amdgcn_mfma_f32_16x16x32_bf16(a[i], bv[j], S[i][j], 0, 0, 0);
        }
        #pragma unroll
        for (int i = 0; i < 4; ++i)
            #pragma unroll
            for (int j = 0; j < 4; ++j)
                #pragma unroll
                for (int r = 0; r < 4; ++r) {
                    float pv = __expf(S[i][j][r] * scale);   // logits bounded; no max-subtract
                    rst[i][r] += pv;
                    P[i * 16 + fg * 4 + r][sc * 64 + j * 16 + fr] = f2bf(pv);
                }
    }
    __syncthreads();
    #pragma unroll
    for (int i = 0; i < 4; ++i)
        #pragma unroll
        for (int r = 0; r < 4; ++r) {
            float t = rst[i][r];
            t += __shfl_xor(t, 1); t += __shfl_xor(t, 2);
            t += __shfl_xor(t, 4); t += __shfl_xor(t, 8);
            if (fr == 0) atomicAdd(&agg_sum[(size_t)bh * 64 + i * 16 + fg * 4 + r], t);
        }
    const u16* vbase = vT + ((size_t)(b * 8 + g) * 128 + fr) * T_ + t0 + fg * 8;
    #pragma unroll
    for (int dh = 0; dh < 2; ++dh) {
        f32x4 O[4][4] = {};
        #pragma unroll
        for (int ks = 0; ks < 4; ++ks) {
            bf16x8 pa[4], vv[4];
            #pragma unroll
            for (int i = 0; i < 4; ++i) pa[i] = *(const bf16x8*)&P[i * 16 + fr][ks * 32 + fg * 8];
            #pragma unroll
            for (int j = 0; j < 4; ++j) vv[j] = *(const bf16x8*)(vbase + ((size_t)dh * 64 + j * 16) * T_ + ks * 32);
            #pragma unroll
            for (int i = 0; i < 4; ++i)
                #pragma unroll
                for (int j = 0; j < 4; ++j)
                    O[i][j] = __builtin_amdgcn_mfma_f32_16x16x32_bf16(pa[i], vv[j], O[i][j], 0, 0, 0);
        }
        #pragma unroll
        for (int i = 0; i < 4; ++i)
            #pragma unroll
            for (int j = 0; j < 4; ++j)
                #pragma unroll
                for (int r = 0; r < 4; ++r)
                    atomicAdd(&agg_acc[((size_t)bh * 64 + i * 16 + fg * 4 + r) * 128 + dh * 64 + j * 16 + fr],
                              O[i][j][r]);
    }
}

// ---------------- mid = K_mm_inv @ (agg/sum), store transposed bf16 ----------------
__global__ __launch_bounds__(256) void mid_kernel(
    const float* __restrict__ inv, const float* __restrict__ agg_acc,
    const float* __restrict__ agg_sum, u16* __restrict__ midt)
{
    const int bh = blockIdx.x;
    const int tid = threadIdx.x;
    __shared__ float invl[64][68];
    __shared__ float an[64][129];
    for (int idx = tid; idx < 4096; idx += 256)
        invl[idx >> 6][idx & 63] = inv[(size_t)bh * 4096 + idx];
    for (int idx = tid; idx < 8192; idx += 256) {
        int j = idx >> 7, d = idx & 127;
        an[j][d] = agg_acc[((size_t)bh * 64 + j) * 128 + d] / agg_sum[(size_t)bh * 64 + j];
    }
    __syncthreads();
    const int m = tid >> 2, dq = tid & 3;
    float accv[32] = {};
    for (int j = 0; j < 64; ++j) {
        float a = invl[m][j];
        #pragma unroll
        for (int dd = 0; dd < 32; ++dd)
            accv[dd] += a * an[j][dq * 32 + dd];
    }
    for (int dd = 0; dd < 32; ++dd)
        midt[(size_t)bh * 8192 + (dq * 32 + dd) * 64 + m] = f2bf(accv[dd]);
}

// ---------------- K_qm softmax @ mid, fused per 128-row tile ----------------
__global__ __launch_bounds__(256) void attn_qm_kernel(
    const u16* __restrict__ qb, const u16* __restrict__ klb,
    const u16* __restrict__ midt, u16* __restrict__ ao)
{
    const int bid = blockIdx.x;
    const int tile = bid & 63;
    const int bh = bid >> 6;
    const int b = bh >> 4, h = bh & 15;
    const int w = threadIdx.x >> 6;
    const int lane = threadIdx.x & 63;
    const int fr = lane & 15, fg = lane >> 4;
    const int trow0 = tile * 128 + w * 32;
    const float scale = 0.08838834764831845f;
    __shared__ u16 Pl[4][32][72];

    f32x4 S[2][4] = {};
    const u16* qbase = qb + ((size_t)(b * T_ + trow0 + fr)) * 2048 + h * 128 + fg * 8;
    const u16* kbase = klb + ((size_t)bh * 64 + fr) * 128 + fg * 8;
    #pragma unroll
    for (int ks = 0; ks < 4; ++ks) {
        bf16x8 a[2], bv[4];
        #pragma unroll
        for (int i = 0; i < 2; ++i) a[i] = *(const bf16x8*)(qbase + (size_t)i * 16 * 2048 + ks * 32);
        #pragma unroll
        for (int j = 0; j < 4; ++j) bv[j] = *(const bf16x8*)(kbase + (size_t)j * 16 * 128 + ks * 32);
        #pragma unroll
        for (int i = 0; i < 2; ++i)
            #pragma unroll
            for (int j = 0; j < 4; ++j)
                S[i][j] = __builtin_amdgcn_mfma_f32_16x16x32_bf16(a[i], bv[j], S[i][j], 0, 0, 0);
    }
    #pragma unroll
    for (int i = 0; i < 2; ++i) {
        float rsv[4] = {0.f, 0.f, 0.f, 0.f};
        #pragma unroll
        for (int j = 0; j < 4; ++j)
            #pragma unroll
            for (int r = 0; r < 4; ++r) {
                float pv = __expf(S[i][j][r] * scale);
                S[i][j][r] = pv;
                rsv[r] += pv;
            }
        #pragma unroll
        for (int r = 0; r < 4; ++r) {
            float t = rsv[r];
            t += __shfl_xor(t, 1); t += __shfl_xor(t, 2);
            t += __shfl_xor(t, 4); t += __shfl_xor(t, 8);
            rsv[r] = 1.f / t;
        }
        #pragma unroll
        for (int j = 0; j < 4; ++j)
            #pragma unroll
            for (int r = 0; r < 4; ++r)
                Pl[w][i * 16 + fg * 4 + r][j * 16 + fr] = f2bf(S[i][j][r] * rsv[r]);
    }
    __syncthreads();
    f32x4 O[2][8] = {};
    const u16* mbase = midt + ((size_t)bh * 128 + fr) * 64 + fg * 8;
    #pragma unroll
    for (int ks = 0; ks < 2; ++ks) {
        bf16x8 pa[2], mb[8];
        #pragma unroll
        for (int i = 0; i < 2; ++i) pa[i] = *(const bf16x8*)&Pl[w][i * 16 + fr][ks * 32 + fg * 8];
        #pragma unroll
        for (int j = 0; j < 8; ++j) mb[j] = *(const bf16x8*)(mbase + (size_t)j * 16 * 64 + ks * 32);
        #pragma unroll
        for (int i = 0; i < 2; ++i)
            #pragma unroll
            for (int j = 0; j < 8; ++j)
                O[i][j] = __builtin_amdgcn_mfma_f32_16x16x32_bf16(pa[i], mb[j], O[i][j], 0, 0, 0);
    }
    u16* obase = ao + ((size_t)(b * T_ + trow0 + fg * 4)) * 2048 + h * 128 + fr;
    #pragma unroll
    for (int i = 0; i < 2; ++i)
        #pragma unroll
        for (int j = 0; j < 8; ++j)
            #pragma unroll
            for (int r = 0; r < 4; ++r)
                obase[((size_t)i * 16 + r) * 2048 + j * 16] = f2bf(O[i][j][r]);
}

// ---------------- launch ----------------
extern "C" void kernel_launch(void* const* d_in, const int* in_sizes, int n_in,
                              void* d_out, int out_size, void* d_ws, size_t ws_size,
                              hipStream_t stream)
{
    const float* x    = (const float*)d_in[0];
    const float* Wq   = (const float*)d_in[1];
    const float* Wk   = (const float*)d_in[2];
    const float* Wv   = (const float*)d_in[3];
    const float* Wo   = (const float*)d_in[4];
    const float* Wkp1 = (const float*)d_in[5];
    const float* Wkp2 = (const float*)d_in[6];
    float* out = (float*)d_out;

    char* p = (char*)d_ws;
    auto alloc = [&](size_t bytes) { char* r = p; p += (bytes + 255) & ~(size_t)255; return r; };
    u16*   x_bf     = (u16*)alloc(67108864);
    u16*   q_bf     = (u16*)alloc(67108864);
    u16*   kv_bf    = (u16*)alloc(67108864);
    u16*   Wcat_t   = (u16*)alloc(16777216);
    float* land_raw = (float*)alloc(1572864);
    float* qlf      = (float*)alloc(2097152);
    float* klf      = (float*)alloc(2097152);
    u16*   qlb      = (u16*)alloc(1048576);
    u16*   klb      = (u16*)alloc(1048576);
    float* invb     = (float*)alloc(524288);
    float* agg_acc  = (float*)alloc(2097152);
    float* agg_sum  = (float*)alloc(32768);
    u16*   midt     = (u16*)alloc(1048576);

    u16* k_bf = kv_bf;
    u16* v_bf = kv_bf + (size_t)16384 * 1024;
    u16* vT       = x_bf;    // x_bf dead after gemm1
    u16* attn_out = kv_bf;   // k,v dead after attn_mk + tv
    u16* Wo_t     = Wcat_t;  // Wcat_t dead after gemm1

    (void)hipMemsetAsync(land_raw, 0, 1572864, stream);
    (void)hipMemsetAsync(agg_acc, 0, 2097152, stream);
    (void)hipMemsetAsync(agg_sum, 0, 32768, stream);

    cvt_x_kernel<<<2048, 256, 0, stream>>>(x, x_bf, 16384 * 2048 / 4);
    tconv_kernel<<<dim3(64, 64), dim3(32, 8), 0, stream>>>(Wq, Wcat_t, 2048, 2048);
    tconv_kernel<<<dim3(32, 64), dim3(32, 8), 0, stream>>>(Wk, Wcat_t + (size_t)2048 * 2048, 2048, 1024);
    tconv_kernel<<<dim3(32, 64), dim3(32, 8), 0, stream>>>(Wv, Wcat_t + (size_t)3072 * 2048, 2048, 1024);
    gemm256_kernel<0><<<1024, 512, 0, stream>>>(x_bf, Wcat_t, q_bf, k_bf, v_bf, nullptr, 2048, 16);
    land_gemm_kernel<<<dim3(24, 8), 256, 0, stream>>>(x, Wq, Wk, land_raw);
    proj_kernel<<<4096, 64, 0, stream>>>(land_raw, Wkp1, Wkp2, qlf, klf, qlb, klb);
    pinv_kernel<<<32, 256, 0, stream>>>(qlf, klf, invb);
    tv_kernel<<<dim3(256, 4, 16), dim3(32, 8), 0, stream>>>(v_bf, vT);
    attn_mk_kernel<<<2048, 64, 0, stream>>>(qlb, k_bf, vT, agg_acc, agg_sum);
    mid_kernel<<<32, 256, 0, stream>>>(invb, agg_acc, agg_sum, midt);
    tconv_kernel<<<dim3(64, 64), dim3(32, 8), 0, stream>>>(Wo, Wo_t, 2048, 2048);
    attn_qm_kernel<<<2048, 256, 0, stream>>>(q_bf, klb, midt, attn_out);
    gemm256_kernel<1><<<512, 512, 0, stream>>>(attn_out, Wo_t, nullptr, nullptr, nullptr, out, 2048, 8);
}

// Round 6
// 1065.508 us; speedup vs baseline: 1.1536x; 1.1536x over previous
//
#include <hip/hip_runtime.h>

// Landmark (Nystrom) attention, MI355X/gfx950.
// B=2 T=8192 Dm=2048 H=16 Hkv=8 Dh=128 M=64 RANK=64 NIT=6
// Round 5 (resubmit after GPU acquisition timeout): revert GEMM to round-2
// schedule (round-3 read-ahead regressed); remove ALL global atomics:
// attn_mk -> per-chunk partials in d_out scratch + reduce kernel;
// land_gemm -> split-K partials summed in proj; drop memsets.

#define B_ 2
#define T_ 8192
#define DM 2048
#define H_ 16
#define DH 128
#define NIT 6

typedef unsigned short u16;
typedef __attribute__((ext_vector_type(8))) short bf16x8;
typedef __attribute__((ext_vector_type(4))) float f32x4;
typedef __attribute__((ext_vector_type(4))) unsigned short u16x4;

__device__ __forceinline__ u16 f2bf(float f) {
    unsigned u = __float_as_uint(f);
    u += 0x7FFFu + ((u >> 16) & 1u);
    return (u16)(u >> 16);
}

__device__ __forceinline__ void async16(const void* g, void* l) {
    __builtin_amdgcn_global_load_lds((const __attribute__((address_space(1))) void*)g,
                                     (__attribute__((address_space(3))) void*)l,
                                     16, 0, 0);
}

// ---------------- elementwise f32 -> bf16 ----------------
__global__ void cvt_x_kernel(const float* __restrict__ x, u16* __restrict__ xb, int n4) {
    int i = blockIdx.x * blockDim.x + threadIdx.x;
    int stride = gridDim.x * blockDim.x;
    for (; i < n4; i += stride) {
        float4 v = ((const float4*)x)[i];
        u16x4 o;
        o.x = f2bf(v.x); o.y = f2bf(v.y); o.z = f2bf(v.z); o.w = f2bf(v.w);
        ((u16x4*)xb)[i] = o;
    }
}

// ---------------- transpose + convert f32 (R x C) -> bf16 (C x R) ----------------
__global__ void tconv_kernel(const float* __restrict__ src, u16* __restrict__ dst, int R, int C) {
    __shared__ float tl[32][33];
    int c0 = blockIdx.x * 32, r0 = blockIdx.y * 32;
    int tx = threadIdx.x, ty = threadIdx.y;
    #pragma unroll
    for (int i = ty; i < 32; i += 8)
        tl[i][tx] = src[(size_t)(r0 + i) * C + c0 + tx];
    __syncthreads();
    #pragma unroll
    for (int i = ty; i < 32; i += 8)
        dst[(size_t)(c0 + i) * R + r0 + tx] = f2bf(tl[tx][i]);
}

// ---------------- transpose bf16 v (per b,g: [T][128] -> [128][T]) ----------------
__global__ void tv_kernel(const u16* __restrict__ v, u16* __restrict__ vT) {
    int bg = blockIdx.z;
    const u16* src = v + (size_t)(bg >> 3) * T_ * 1024 + (bg & 7) * DH;
    u16* dst = vT + (size_t)bg * DH * T_;
    __shared__ u16 tl[32][33];
    int t0 = blockIdx.x * 32, d0 = blockIdx.y * 32;
    int tx = threadIdx.x, ty = threadIdx.y;
    #pragma unroll
    for (int i = ty; i < 32; i += 8)
        tl[i][tx] = src[(size_t)(t0 + i) * 1024 + d0 + tx];
    __syncthreads();
    #pragma unroll
    for (int i = ty; i < 32; i += 8)
        dst[(size_t)(d0 + i) * T_ + t0 + tx] = tl[tx][i];
}

// ==================== 256x256 8-phase bf16 GEMM (round-2 schedule) ====================
// Per phase: {ds_read this quadrant's frags | stage 1 half-tile | BAR | lgkm0 |
// setprio 16xMFMA | BAR}. vmcnt(6) once per K-tile at phase 4. LDS swizzle
// byte^=((fr&7)<<4) on ds_read + inverse-swizzled global source (rule #21).

#define BAR()   __builtin_amdgcn_s_barrier()
#define SB0()   __builtin_amdgcn_sched_barrier(0)
#define LGKM0() do { asm volatile("s_waitcnt lgkmcnt(0)" ::: "memory"); SB0(); } while (0)
#define VM6()   do { asm volatile("s_waitcnt vmcnt(6)" ::: "memory"); } while (0)

#define RD_A(S, BUF, H) do {                                                  \
    const char* _p = lA_rd + (BUF) * 32768 + (H) * 16384;                     \
    _Pragma("unroll") for (int _m = 0; _m < 4; ++_m) {                        \
        Af[S][_m][0] = *(const bf16x8*)(_p + _m * 2048 + kswz0);              \
        Af[S][_m][1] = *(const bf16x8*)(_p + _m * 2048 + kswz1);              \
    }                                                                         \
} while (0)

#define RD_B(S, BUF, H) do {                                                  \
    const char* _p = lB_rd + (BUF) * 32768 + (H) * 16384;                     \
    _Pragma("unroll") for (int _n = 0; _n < 2; ++_n) {                        \
        Bf[S][_n][0] = *(const bf16x8*)(_p + _n * 2048 + kswz0);              \
        Bf[S][_n][1] = *(const bf16x8*)(_p + _n * 2048 + kswz1);              \
    }                                                                         \
} while (0)

#define ST_A(BUF, H, T) do {                                                  \
    const u16* _g = gA + (size_t)(H) * 64 * K + (size_t)(T) * 64;             \
    char* _l = lsAst + (BUF) * 32768 + (H) * 16384;                           \
    async16(_g, _l);                                                          \
    async16(_g + (size_t)128 * K, _l + 8192);                                 \
} while (0)

#define ST_B(BUF, H, T) do {                                                  \
    const u16* _g = gB + (size_t)(H) * 32 * K + (size_t)(T) * 64;             \
    char* _l = lsBst + (BUF) * 32768 + (H) * 16384;                           \
    async16(_g, _l);                                                          \
    async16(_g + (size_t)128 * K, _l + 8192);                                 \
} while (0)

#define MFMA_Q(AM, BN)                                                        \
    _Pragma("unroll") for (int _m = 0; _m < 4; ++_m)                          \
    _Pragma("unroll") for (int _n = 0; _n < 2; ++_n)                          \
    _Pragma("unroll") for (int _k = 0; _k < 2; ++_k)                          \
        acc[(AM) * 4 + _m][(BN) * 2 + _n] =                                   \
            __builtin_amdgcn_mfma_f32_16x16x32_bf16(                          \
                Af[AM][_m][_k], Bf[BN][_n][_k],                               \
                acc[(AM) * 4 + _m][(BN) * 2 + _n], 0, 0, 0);

template<int MODE>
__global__ __launch_bounds__(512) void gemm256_kernel(
    const u16* __restrict__ A, const u16* __restrict__ Bt,
    u16* __restrict__ oq, u16* __restrict__ ok, u16* __restrict__ ov,
    float* __restrict__ of, int K, int nxt)
{
    __shared__ u16 lsA[2][2][128][64];   // [buf][half][row][k]
    __shared__ u16 lsB[2][2][128][64];

    const int tid  = threadIdx.x;
    const int lane = tid & 63;
    const int w    = tid >> 6;
    const int wr   = w >> 2, wc = w & 3;
    const int fr   = lane & 15, fg = lane >> 4;

    const int cpx = (int)gridDim.x >> 3;
    const int bid = ((int)blockIdx.x & 7) * cpx + ((int)blockIdx.x >> 3);
    const int bx = bid % nxt, by = bid / nxt;
    const long R0 = (long)by * 256, C0 = (long)bx * 256;

    const int sr = tid >> 3;
    const int sc = tid & 7;
    const int koff = ((sc ^ (sr & 7)) * 8);
    const u16* gA = A  + (R0 + sr) * (size_t)K + koff;
    const u16* gB = Bt + (C0 + (sr >> 5) * 64 + (sr & 31)) * (size_t)K + koff;
    char* lsAst = (char*)lsA + w * 1024;
    char* lsBst = (char*)lsB + w * 1024;

    const int kswz0 = (0 * 64 + fg * 16) ^ ((fr & 7) << 4);
    const int kswz1 = (1 * 64 + fg * 16) ^ ((fr & 7) << 4);
    const char* lA_rd = (const char*)lsA + (wr * 64 + fr) * 128;
    const char* lB_rd = (const char*)lsB + (wc * 32 + fr) * 128;

    f32x4 acc[8][4] = {};
    bf16x8 Af[2][4][2], Bf[2][2][2];

    const int NT = K >> 6;

    ST_A(0, 0, 0); ST_B(0, 0, 0); ST_B(0, 1, 0); ST_A(0, 1, 0);
    ST_A(1, 0, 1); ST_B(1, 0, 1); ST_B(1, 1, 1);
    VM6();
    BAR(); SB0();

    for (int t = 0; t < NT; ++t) {
        const int buf = t & 1;
        // -- phase 1: read A0(t); stage A1(t+1); MFMA Q11(t-1)
        RD_A(0, buf, 0);
        if (t + 1 < NT) ST_A(buf ^ 1, 1, t + 1);
        BAR(); LGKM0();
        __builtin_amdgcn_s_setprio(1);
        if (t > 0) { MFMA_Q(1, 1); }
        __builtin_amdgcn_s_setprio(0);
        BAR(); SB0();
        // -- phase 2: read B0(t); stage A0(t+2); MFMA Q00(t)
        RD_B(0, buf, 0);
        if (t + 2 < NT) ST_A(buf, 0, t + 2);
        BAR(); LGKM0();
        __builtin_amdgcn_s_setprio(1);
        MFMA_Q(0, 0);
        __builtin_amdgcn_s_setprio(0);
        BAR(); SB0();
        // -- phase 3: read B1(t); stage B0(t+2); MFMA Q01(t)
        RD_B(1, buf, 1);
        if (t + 2 < NT) ST_B(buf, 0, t + 2);
        BAR(); LGKM0();
        __builtin_amdgcn_s_setprio(1);
        MFMA_Q(0, 1);
        __builtin_amdgcn_s_setprio(0);
        BAR(); SB0();
        // -- phase 4: read A1(t); stage B1(t+2); vmcnt(6); MFMA Q10(t)
        RD_A(1, buf, 1);
        if (t + 2 < NT) ST_B(buf, 1, t + 2);
        VM6();
        BAR(); LGKM0();
        __builtin_amdgcn_s_setprio(1);
        MFMA_Q(1, 0);
        __builtin_amdgcn_s_setprio(0);
        BAR(); SB0();
    }
    MFMA_Q(1, 1);

    const long rb0 = R0 + wr * 128 + fg * 4;
    const int  cb0 = (int)C0 + wc * 64 + fr;
    #pragma unroll
    for (int mi = 0; mi < 8; ++mi)
        #pragma unroll
        for (int ni = 0; ni < 4; ++ni)
            #pragma unroll
            for (int rr = 0; rr < 4; ++rr) {
                long rg = rb0 + mi * 16 + rr;
                int  nn = cb0 + ni * 16;
                float val = acc[mi][ni][rr];
                if (MODE == 0) {
                    u16 o = f2bf(val);
                    if (nn < 2048)      oq[rg * 2048 + nn] = o;
                    else if (nn < 3072) ok[rg * 1024 + (nn - 2048)] = o;
                    else                ov[rg * 1024 + (nn - 3072)] = o;
                } else {
                    of[rg * 2048 + nn] = val;
                }
            }
}

// ---------------- exact f32 landmark GEMM: land_part[ky][128][3072] = partial ----------------
// grid (24 n-tiles, 8 k-groups); plain stores (no atomics); proj sums the 8 slabs.
__global__ __launch_bounds__(256) void land_gemm_kernel(
    const float* __restrict__ x, const float* __restrict__ Wq,
    const float* __restrict__ Wk, float* __restrict__ land_part)
{
    __shared__ float xs[128][36];
    __shared__ float ws[32][132];
    const int tid = threadIdx.x;
    const int n0 = blockIdx.x * 128;
    const int tm0 = (tid >> 4) * 8, tn0 = (tid & 15) * 8;
    float accr[8][8] = {};

    for (int it = 0; it < 8; ++it) {
        const int k0 = blockIdx.y * 256 + it * 32;
        __syncthreads();
        for (int idx = tid * 4; idx < 4096; idx += 1024) {
            int r = idx >> 5, c = idx & 31;
            *(float4*)&xs[r][c] =
                *(const float4*)&x[((size_t)(r >> 6) * T_ + (r & 63) * 128) * DM + k0 + c];
        }
        if (n0 < 2048) {
            for (int idx = tid * 4; idx < 4096; idx += 1024) {
                int k = idx >> 7, c = idx & 127;
                *(float4*)&ws[k][c] = *(const float4*)&Wq[(size_t)(k0 + k) * 2048 + n0 + c];
            }
        } else {
            for (int idx = tid * 4; idx < 4096; idx += 1024) {
                int k = idx >> 7, c = idx & 127;
                *(float4*)&ws[k][c] = *(const float4*)&Wk[(size_t)(k0 + k) * 1024 + (n0 - 2048) + c];
            }
        }
        __syncthreads();
        for (int k = 0; k < 32; ++k) {
            float a[8];
            #pragma unroll
            for (int i = 0; i < 8; ++i) a[i] = xs[tm0 + i][k];
            f32x4 b0 = *(const f32x4*)&ws[k][tn0];
            f32x4 b1 = *(const f32x4*)&ws[k][tn0 + 4];
            #pragma unroll
            for (int i = 0; i < 8; ++i) {
                accr[i][0] += a[i] * b0[0]; accr[i][1] += a[i] * b0[1];
                accr[i][2] += a[i] * b0[2]; accr[i][3] += a[i] * b0[3];
                accr[i][4] += a[i] * b1[0]; accr[i][5] += a[i] * b1[1];
                accr[i][6] += a[i] * b1[2]; accr[i][7] += a[i] * b1[3];
            }
        }
    }
    float* o = land_part + (size_t)blockIdx.y * 393216;
    for (int i = 0; i < 8; ++i)
        for (int j = 0; j < 8; ++j)
            o[(size_t)(tm0 + i) * 3072 + n0 + tn0 + j] = accr[i][j];
}

// ---------------- kernel_proj on landmarks (f32 exact; sums 8 k-partials) ----------------
__global__ void proj_kernel(const float* __restrict__ land_part,
    const float* __restrict__ Wkp1, const float* __restrict__ Wkp2,
    float* __restrict__ qlf, float* __restrict__ klf,
    u16* __restrict__ qlb, u16* __restrict__ klb)
{
    const int bid = blockIdx.x;
    const int type = bid & 1;
    const int m = (bid >> 1) & 63;
    const int bh = bid >> 7;
    const int b = bh >> 4, h = bh & 15;
    const int lane = threadIdx.x;
    const int lm = b * 64 + m;
    const size_t off = (type == 0)
        ? (size_t)lm * 3072 + h * 128
        : (size_t)lm * 3072 + 2048 + (h >> 1) * 128;
    __shared__ float zb[128];
    __shared__ float sb[64];
    float z0 = 0.f, z1 = 0.f;
    #pragma unroll
    for (int s = 0; s < 8; ++s) {
        z0 += land_part[(size_t)s * 393216 + off + lane];
        z1 += land_part[(size_t)s * 393216 + off + lane + 64];
    }
    zb[lane] = z0; zb[lane + 64] = z1;
    __syncthreads();
    float hsum = 0.f;
    #pragma unroll 4
    for (int d = 0; d < 128; ++d) hsum += zb[d] * Wkp1[d * 64 + lane];
    sb[lane] = hsum / (1.f + __expf(-hsum));
    __syncthreads();
    float o0 = z0, o1 = z1;
    #pragma unroll 4
    for (int j = 0; j < 64; ++j) {
        float sj = sb[j];
        o0 += sj * Wkp2[j * 128 + lane];
        o1 += sj * Wkp2[j * 128 + lane + 64];
    }
    size_t oidx = ((size_t)bh * 64 + m) * 128 + lane;
    float* fo = (type == 0) ? qlf : klf;
    u16*   bo = (type == 0) ? qlb : klb;
    fo[oidx] = o0; fo[oidx + 64] = o1;
    bo[oidx] = f2bf(o0); bo[oidx + 64] = f2bf(o1);
}

// ---------------- K_mm softmax + Newton pinv (f32, one block per bh) ----------------
__global__ __launch_bounds__(256) void pinv_kernel(
    const float* __restrict__ qlf, const float* __restrict__ klf, float* __restrict__ inv)
{
    const int bh = blockIdx.x;
    const int tid = threadIdx.x;
    const int m = tid >> 2, nq = tid & 3, n0b = nq * 16;
    __shared__ float Am[64][68];
    __shared__ float Z[64][68];
    __shared__ float Wm[64][68];
    __shared__ float cs[64], rsn[64];
    __shared__ float vsc;
    const float scale = 0.08838834764831845f;

    float accr[16] = {};
    const float* qrow = qlf + ((size_t)bh * 64 + m) * 128;
    for (int dc = 0; dc < 4; ++dc) {
        f32x4 qv[8];
        #pragma unroll
        for (int u = 0; u < 8; ++u) qv[u] = *(const f32x4*)&qrow[dc * 32 + u * 4];
        for (int nn = 0; nn < 16; ++nn) {
            const float* kp = klf + ((size_t)bh * 64 + n0b + nn) * 128 + dc * 32;
            float s = 0.f;
            #pragma unroll
            for (int u = 0; u < 8; ++u) {
                f32x4 kv = *(const f32x4*)&kp[u * 4];
                s += qv[u][0]*kv[0] + qv[u][1]*kv[1] + qv[u][2]*kv[2] + qv[u][3]*kv[3];
            }
            accr[nn] += s;
        }
    }
    float rsum = 0.f;
    #pragma unroll
    for (int nn = 0; nn < 16; ++nn) { accr[nn] = __expf(accr[nn] * scale); rsum += accr[nn]; }
    rsum += __shfl_xor(rsum, 1);
    rsum += __shfl_xor(rsum, 2);
    float rinv = 1.f / rsum;
    #pragma unroll
    for (int nn = 0; nn < 16; ++nn) Am[m][n0b + nn] = accr[nn] * rinv;
    __syncthreads();
    if (tid < 64) {
        float s = 0.f;
        for (int i = 0; i < 64; ++i) s += Am[i][tid];
        cs[tid] = s;
    } else if (tid < 128) {
        int r = tid - 64; float s = 0.f;
        for (int j = 0; j < 64; ++j) s += Am[r][j];
        rsn[r] = s;
    }
    __syncthreads();
    if (tid == 0) {
        float n1 = 0.f, ni = 0.f;
        for (int i = 0; i < 64; ++i) { n1 = fmaxf(n1, cs[i]); ni = fmaxf(ni, rsn[i]); }
        float pr = n1 * ni; if (pr < 1e-7f) pr = 1e-7f;
        vsc = 1.f / pr;
    }
    __syncthreads();
    {
        float v = vsc;
        for (int u = 0; u < 16; ++u) {
            int idx = tid * 16 + u;
            Z[idx >> 6][idx & 63] = Am[idx & 63][idx >> 6] * v;
        }
    }
    for (int it = 0; it < NIT; ++it) {
        __syncthreads();
        float wacc[16] = {};
        for (int k = 0; k < 64; ++k) {
            float a = Am[m][k];
            f32x4 z0 = *(const f32x4*)&Z[k][n0b];
            f32x4 z1 = *(const f32x4*)&Z[k][n0b + 4];
            f32x4 z2 = *(const f32x4*)&Z[k][n0b + 8];
            f32x4 z3 = *(const f32x4*)&Z[k][n0b + 12];
            #pragma unroll
            for (int u = 0; u < 4; ++u) {
                wacc[u]      += a * z0[u];
                wacc[u + 4]  += a * z1[u];
                wacc[u + 8]  += a * z2[u];
                wacc[u + 12] += a * z3[u];
            }
        }
        #pragma unroll
        for (int nn = 0; nn < 16; ++nn) Wm[m][n0b + nn] = wacc[nn];
        __syncthreads();
        float zacc[16] = {};
        for (int k = 0; k < 64; ++k) {
            float zk = Z[m][k];
            f32x4 w0 = *(const f32x4*)&Wm[k][n0b];
            f32x4 w1 = *(const f32x4*)&Wm[k][n0b + 4];
            f32x4 w2 = *(const f32x4*)&Wm[k][n0b + 8];
            f32x4 w3 = *(const f32x4*)&Wm[k][n0b + 12];
            #pragma unroll
            for (int u = 0; u < 4; ++u) {
                zacc[u]      += zk * w0[u];
                zacc[u + 4]  += zk * w1[u];
                zacc[u + 8]  += zk * w2[u];
                zacc[u + 12] += zk * w3[u];
            }
        }
        #pragma unroll
        for (int nn = 0; nn < 16; ++nn) zacc[nn] = 2.f * Z[m][n0b + nn] - zacc[nn];
        __syncthreads();
        #pragma unroll
        for (int nn = 0; nn < 16; ++nn) Z[m][n0b + nn] = zacc[nn];
    }
    __syncthreads();
    for (int u = 0; u < 16; ++u) {
        int idx = tid * 16 + u;
        inv[(size_t)bh * 4096 + idx] = Z[idx >> 6][idx & 63];
    }
}

// ---------------- K_mk @ v flash chunks: per-chunk partials, NO atomics ----------------
// grid = bh(32) x chunk(64 x 128 keys); pacc[chunk][bh][64][128], psum[chunk][bh][64].
__global__ __launch_bounds__(64) void attn_mk_kernel(
    const u16* __restrict__ qlb, const u16* __restrict__ kb,
    const u16* __restrict__ vT, float* __restrict__ pacc, float* __restrict__ psum)
{
    const int bid = blockIdx.x;
    const int chunk = bid & 63;
    const int bh = bid >> 6;
    const int b = bh >> 4, h = bh & 15, g = h >> 1;
    const int t0 = chunk * 128;
    const int lane = threadIdx.x;
    const int fr = lane & 15, fg = lane >> 4;
    const float scale = 0.08838834764831845f;
    __shared__ u16 P[64][136];

    float rst[4][4] = {};
    const u16* qbase = qlb + ((size_t)bh * 64 + fr) * 128 + fg * 8;

    for (int sc = 0; sc < 2; ++sc) {
        f32x4 S[4][4] = {};
        const u16* kbase = kb + ((size_t)(b * T_ + t0 + sc * 64 + fr)) * 1024 + g * 128 + fg * 8;
        #pragma unroll
        for (int ks = 0; ks < 4; ++ks) {
            bf16x8 a[4], bv[4];
            #pragma unroll
            for (int i = 0; i < 4; ++i) a[i] = *(const bf16x8*)(qbase + (size_t)i * 16 * 128 + ks * 32);
            #pragma unroll
            for (int j = 0; j < 4; ++j) bv[j] = *(const bf16x8*)(kbase + (size_t)j * 16 * 1024 + ks * 32);
            #pragma unroll
            for (int i = 0; i < 4; ++i)
                #pragma unroll
                for (int j = 0; j < 4; ++j)
                    S[i][j] = __builtin_amdgcn_mfma_f32_16x16x32_bf16(a[i], bv[j], S[i][j], 0, 0, 0);
        }
        #pragma unroll
        for (int i = 0; i < 4; ++i)
            #pragma unroll
            for (int j = 0; j < 4; ++j)
                #pragma unroll
                for (int r = 0; r < 4; ++r) {
                    float pv = __expf(S[i][j][r] * scale);   // logits bounded; no max-subtract
                    rst[i][r] += pv;
                    P[i * 16 + fg * 4 + r][sc * 64 + j * 16 + fr] = f2bf(pv);
                }
    }
    __syncthreads();
    #pragma unroll
    for (int i = 0; i < 4; ++i)
        #pragma unroll
        for (int r = 0; r < 4; ++r) {
            float t = rst[i][r];
            t += __shfl_xor(t, 1); t += __shfl_xor(t, 2);
            t += __shfl_xor(t, 4); t += __shfl_xor(t, 8);
            if (fr == 0) psum[((size_t)chunk * 32 + bh) * 64 + i * 16 + fg * 4 + r] = t;
        }
    float* pslab = pacc + (((size_t)chunk * 32 + bh) * 64) * 128;
    const u16* vbase = vT + ((size_t)(b * 8 + g) * 128 + fr) * T_ + t0 + fg * 8;
    #pragma unroll
    for (int dh = 0; dh < 2; ++dh) {
        f32x4 O[4][4] = {};
        #pragma unroll
        for (int ks = 0; ks < 4; ++ks) {
            bf16x8 pa[4], vv[4];
            #pragma unroll
            for (int i = 0; i < 4; ++i) pa[i] = *(const bf16x8*)&P[i * 16 + fr][ks * 32 + fg * 8];
            #pragma unroll
            for (int j = 0; j < 4; ++j) vv[j] = *(const bf16x8*)(vbase + ((size_t)dh * 64 + j * 16) * T_ + ks * 32);
            #pragma unroll
            for (int i = 0; i < 4; ++i)
                #pragma unroll
                for (int j = 0; j < 4; ++j)
                    O[i][j] = __builtin_amdgcn_mfma_f32_16x16x32_bf16(pa[i], vv[j], O[i][j], 0, 0, 0);
        }
        #pragma unroll
        for (int i = 0; i < 4; ++i)
            #pragma unroll
            for (int j = 0; j < 4; ++j)
                #pragma unroll
                for (int r = 0; r < 4; ++r)
                    pslab[(size_t)(i * 16 + fg * 4 + r) * 128 + dh * 64 + j * 16 + fr] = O[i][j][r];
    }
}

// ---------------- reduce 64 chunk-partials -> an[bh][64][128] = acc/sum ----------------
__global__ __launch_bounds__(256) void reduce_mk_kernel(
    const float* __restrict__ pacc, const float* __restrict__ psum,
    float* __restrict__ an)
{
    const int bh = blockIdx.x;
    const int tid = threadIdx.x;
    __shared__ float ss[64];
    if (tid < 64) {
        float s = 0.f;
        for (int c = 0; c < 64; ++c) s += psum[((size_t)c * 32 + bh) * 64 + tid];
        ss[tid] = s;
    }
    __syncthreads();
    const int r = tid >> 2;
    const int d0 = (tid & 3) * 32;
    f32x4 acc[8] = {};
    for (int c = 0; c < 64; ++c) {
        const float* p = pacc + (((size_t)c * 32 + bh) * 64 + r) * 128 + d0;
        #pragma unroll
        for (int u = 0; u < 8; ++u) {
            f32x4 v = *(const f32x4*)(p + u * 4);
            acc[u][0] += v[0]; acc[u][1] += v[1];
            acc[u][2] += v[2]; acc[u][3] += v[3];
        }
    }
    const float rinv = 1.f / ss[r];
    float* o = an + ((size_t)bh * 64 + r) * 128 + d0;
    #pragma unroll
    for (int u = 0; u < 8; ++u) {
        o[u * 4 + 0] = acc[u][0] * rinv; o[u * 4 + 1] = acc[u][1] * rinv;
        o[u * 4 + 2] = acc[u][2] * rinv; o[u * 4 + 3] = acc[u][3] * rinv;
    }
}

// ---------------- mid = K_mm_inv @ an, store transposed bf16 ----------------
__global__ __launch_bounds__(256) void mid_kernel(
    const float* __restrict__ inv, const float* __restrict__ an_g,
    u16* __restrict__ midt)
{
    const int bh = blockIdx.x;
    const int tid = threadIdx.x;
    __shared__ float invl[64][68];
    __shared__ float an[64][129];
    for (int idx = tid; idx < 4096; idx += 256)
        invl[idx >> 6][idx & 63] = inv[(size_t)bh * 4096 + idx];
    for (int idx = tid; idx < 8192; idx += 256) {
        int j = idx >> 7, d = idx & 127;
        an[j][d] = an_g[((size_t)bh * 64 + j) * 128 + d];
    }
    __syncthreads();
    const int m = tid >> 2, dq = tid & 3;
    float accv[32] = {};
    for (int j = 0; j < 64; ++j) {
        float a = invl[m][j];
        #pragma unroll
        for (int dd = 0; dd < 32; ++dd)
            accv[dd] += a * an[j][dq * 32 + dd];
    }
    for (int dd = 0; dd < 32; ++dd)
        midt[(size_t)bh * 8192 + (dq * 32 + dd) * 64 + m] = f2bf(accv[dd]);
}

// ---------------- K_qm softmax @ mid, fused per 128-row tile ----------------
__global__ __launch_bounds__(256) void attn_qm_kernel(
    const u16* __restrict__ qb, const u16* __restrict__ klb,
    const u16* __restrict__ midt, u16* __restrict__ ao)
{
    const int bid = blockIdx.x;
    const int tile = bid & 63;
    const int bh = bid >> 6;
    const int b = bh >> 4, h = bh & 15;
    const int w = threadIdx.x >> 6;
    const int lane = threadIdx.x & 63;
    const int fr = lane & 15, fg = lane >> 4;
    const int trow0 = tile * 128 + w * 32;
    const float scale = 0.08838834764831845f;
    __shared__ u16 Pl[4][32][72];

    f32x4 S[2][4] = {};
    const u16* qbase = qb + ((size_t)(b * T_ + trow0 + fr)) * 2048 + h * 128 + fg * 8;
    const u16* kbase = klb + ((size_t)bh * 64 + fr) * 128 + fg * 8;
    #pragma unroll
    for (int ks = 0; ks < 4; ++ks) {
        bf16x8 a[2], bv[4];
        #pragma unroll
        for (int i = 0; i < 2; ++i) a[i] = *(const bf16x8*)(qbase + (size_t)i * 16 * 2048 + ks * 32);
        #pragma unroll
        for (int j = 0; j < 4; ++j) bv[j] = *(const bf16x8*)(kbase + (size_t)j * 16 * 128 + ks * 32);
        #pragma unroll
        for (int i = 0; i < 2; ++i)
            #pragma unroll
            for (int j = 0; j < 4; ++j)
                S[i][j] = __builtin_amdgcn_mfma_f32_16x16x32_bf16(a[i], bv[j], S[i][j], 0, 0, 0);
    }
    #pragma unroll
    for (int i = 0; i < 2; ++i) {
        float rsv[4] = {0.f, 0.f, 0.f, 0.f};
        #pragma unroll
        for (int j = 0; j < 4; ++j)
            #pragma unroll
            for (int r = 0; r < 4; ++r) {
                float pv = __expf(S[i][j][r] * scale);
                S[i][j][r] = pv;
                rsv[r] += pv;
            }
        #pragma unroll
        for (int r = 0; r < 4; ++r) {
            float t = rsv[r];
            t += __shfl_xor(t, 1); t += __shfl_xor(t, 2);
            t += __shfl_xor(t, 4); t += __shfl_xor(t, 8);
            rsv[r] = 1.f / t;
        }
        #pragma unroll
        for (int j = 0; j < 4; ++j)
            #pragma unroll
            for (int r = 0; r < 4; ++r)
                Pl[w][i * 16 + fg * 4 + r][j * 16 + fr] = f2bf(S[i][j][r] * rsv[r]);
    }
    __syncthreads();
    f32x4 O[2][8] = {};
    const u16* mbase = midt + ((size_t)bh * 128 + fr) * 64 + fg * 8;
    #pragma unroll
    for (int ks = 0; ks < 2; ++ks) {
        bf16x8 pa[2], mb[8];
        #pragma unroll
        for (int i = 0; i < 2; ++i) pa[i] = *(const bf16x8*)&Pl[w][i * 16 + fr][ks * 32 + fg * 8];
        #pragma unroll
        for (int j = 0; j < 8; ++j) mb[j] = *(const bf16x8*)(mbase + (size_t)j * 16 * 64 + ks * 32);
        #pragma unroll
        for (int i = 0; i < 2; ++i)
            #pragma unroll
            for (int j = 0; j < 8; ++j)
                O[i][j] = __builtin_amdgcn_mfma_f32_16x16x32_bf16(pa[i], mb[j], O[i][j], 0, 0, 0);
    }
    u16* obase = ao + ((size_t)(b * T_ + trow0 + fg * 4)) * 2048 + h * 128 + fr;
    #pragma unroll
    for (int i = 0; i < 2; ++i)
        #pragma unroll
        for (int j = 0; j < 8; ++j)
            #pragma unroll
            for (int r = 0; r < 4; ++r)
                obase[((size_t)i * 16 + r) * 2048 + j * 16] = f2bf(O[i][j][r]);
}

// ---------------- launch ----------------
extern "C" void kernel_launch(void* const* d_in, const int* in_sizes, int n_in,
                              void* d_out, int out_size, void* d_ws, size_t ws_size,
                              hipStream_t stream)
{
    const float* x    = (const float*)d_in[0];
    const float* Wq   = (const float*)d_in[1];
    const float* Wk   = (const float*)d_in[2];
    const float* Wv   = (const float*)d_in[3];
    const float* Wo   = (const float*)d_in[4];
    const float* Wkp1 = (const float*)d_in[5];
    const float* Wkp2 = (const float*)d_in[6];
    float* out = (float*)d_out;

    char* p = (char*)d_ws;
    auto alloc = [&](size_t bytes) { char* r = p; p += (bytes + 255) & ~(size_t)255; return r; };
    u16*   x_bf      = (u16*)alloc(67108864);    // 16384x2048 bf16; later aliased by vT
    u16*   q_bf      = (u16*)alloc(67108864);
    u16*   kv_bf     = (u16*)alloc(67108864);    // k | v; later attn_out
    u16*   Wcat_t    = (u16*)alloc(16777216);    // later Wo_t
    float* land_part = (float*)alloc(12582912);  // [8][128][3072]
    float* qlf       = (float*)alloc(2097152);
    float* klf       = (float*)alloc(2097152);
    u16*   qlb       = (u16*)alloc(1048576);
    u16*   klb       = (u16*)alloc(1048576);
    float* invb      = (float*)alloc(524288);
    float* an        = (float*)alloc(1048576);   // [32][64][128]
    u16*   midt      = (u16*)alloc(1048576);

    u16* k_bf = kv_bf;
    u16* v_bf = kv_bf + (size_t)16384 * 1024;
    u16* vT       = x_bf;    // x_bf dead after gemm1
    u16* attn_out = kv_bf;   // k,v dead after attn_mk + tv
    u16* Wo_t     = Wcat_t;  // Wcat_t dead after gemm1

    // d_out doubles as scratch for attn_mk partials (fully overwritten by gemm2):
    float* pacc = out;                    // [64][32][64][128] f32 = 67.1 MB
    float* psum = out + (size_t)16777216; // [64][32][64] f32 = 0.5 MB

    cvt_x_kernel<<<2048, 256, 0, stream>>>(x, x_bf, 16384 * 2048 / 4);
    tconv_kernel<<<dim3(64, 64), dim3(32, 8), 0, stream>>>(Wq, Wcat_t, 2048, 2048);
    tconv_kernel<<<dim3(32, 64), dim3(32, 8), 0, stream>>>(Wk, Wcat_t + (size_t)2048 * 2048, 2048, 1024);
    tconv_kernel<<<dim3(32, 64), dim3(32, 8), 0, stream>>>(Wv, Wcat_t + (size_t)3072 * 2048, 2048, 1024);
    gemm256_kernel<0><<<1024, 512, 0, stream>>>(x_bf, Wcat_t, q_bf, k_bf, v_bf, nullptr, 2048, 16);
    land_gemm_kernel<<<dim3(24, 8), 256, 0, stream>>>(x, Wq, Wk, land_part);
    proj_kernel<<<4096, 64, 0, stream>>>(land_part, Wkp1, Wkp2, qlf, klf, qlb, klb);
    pinv_kernel<<<32, 256, 0, stream>>>(qlf, klf, invb);
    tv_kernel<<<dim3(256, 4, 16), dim3(32, 8), 0, stream>>>(v_bf, vT);
    attn_mk_kernel<<<2048, 64, 0, stream>>>(qlb, k_bf, vT, pacc, psum);
    reduce_mk_kernel<<<32, 256, 0, stream>>>(pacc, psum, an);
    mid_kernel<<<32, 256, 0, stream>>>(invb, an, midt);
    tconv_kernel<<<dim3(64, 64), dim3(32, 8), 0, stream>>>(Wo, Wo_t, 2048, 2048);
    attn_qm_kernel<<<2048, 256, 0, stream>>>(q_bf, klb, midt, attn_out);
    gemm256_kernel<1><<<512, 512, 0, stream>>>(attn_out, Wo_t, nullptr, nullptr, nullptr, out, 2048, 8);
}